// Round 7
// baseline (189.974 us; speedup 1.0000x reference)
//
#include <hip/hip_runtime.h>
#include <math.h>

#define NROWS 131072
#define M 8
#define D 128
#define RPB 32   // rows per block; grid = 4096 blocks
#define E_CONST 2.71828182845904523536f

typedef float f32x4 __attribute__((ext_vector_type(4)));

__global__ __launch_bounds__(256) void emma_fused6(
    const float* __restrict__ x, const float* __restrict__ q,
    const float* __restrict__ w, const float* __restrict__ b,
    const float* __restrict__ gammas, const float* __restrict__ G,
    const float* __restrict__ bias, const float* __restrict__ qmin,
    float* __restrict__ out)
{
    __shared__ float s_beta[RPB][M];

    const int tid = threadIdx.x;
    const int r   = tid >> 3;     // row within block (0..31)
    const int i   = tid & 7;      // mode this thread owns
    const int n   = blockIdx.x * RPB + r;

    // ---- Phase 1: 8 threads per row, one mode each (~6 us aggregate).
    {
        const f32x4 q0 = *reinterpret_cast<const f32x4*>(q + (size_t)n * M);
        const f32x4 q1 = *reinterpret_cast<const f32x4*>(q + (size_t)n * M + 4);
        float qv[M] = {q0.x, q0.y, q0.z, q0.w, q1.x, q1.y, q1.z, q1.w};

        float lphi[M];
        #pragma unroll
        for (int m = 0; m < M; ++m) {
            float corr = fmaxf(qv[m] - qmin[m] + E_CONST, E_CONST);
            float phi  = fmaf(w[m], corr, corr) + b[m];   // (1+w)*corr + b
            lphi[m] = logf(phi);                           // phi >= e > 0
        }

        float myl = lphi[0];
        #pragma unroll
        for (int m = 1; m < M; ++m) if (i == m) myl = lphi[m];

        float s = 0.0f;
        #pragma unroll
        for (int j = 0; j < M; ++j) {
            int lo = (i < j) ? i : j;
            int hi = (i < j) ? j : i;
            float g = gammas[lo * M + hi];
            s += expf(fmaf(g, myl - lphi[j], lphi[j]));
        }

        float neg = -s;                                    // TAU = 1
        float mx = neg;
        #pragma unroll
        for (int d = 1; d < 8; d <<= 1) mx = fmaxf(mx, __shfl_xor(mx, d, 8));
        float e = expf(neg - mx);
        float sum = e;
        #pragma unroll
        for (int d = 1; d < 8; d <<= 1) sum += __shfl_xor(sum, d, 8);
        float alpha = e / sum;

        float t = tanhf(fmaf(G[i], alpha, bias[i]));
        s_beta[r][i] = fmaxf(t, 0.0f);
    }
    __syncthreads();

    // ---- Phase 2: wave-uniform zero-mode load skip + nt streaming.
    // Unit = (mode, row-pair): lanes 0-31 cover row 2p, lanes 32-63 row 2p+1,
    // each 512 B contiguous. Skip condition is wave-uniform (__all) so the
    // global_load is behind a scalar branch: skipped modes fetch NOTHING.
    const size_t base = (size_t)blockIdx.x * (RPB * M * D / 4);  // in float4s
    const f32x4* __restrict__ x4 = reinterpret_cast<const f32x4*>(x) + base;
    f32x4* __restrict__ o4       = reinterpret_cast<f32x4*>(out) + base;

    const int lane = tid & 63;
    const int wv   = tid >> 6;        // wave id 0..3
    const int half = lane >> 5;       // row within pair
    const int l32  = lane & 31;       // float4 within mode segment
    const f32x4 zero4 = {0.f, 0.f, 0.f, 0.f};

#define UNIT(K, UU)                                                          \
    const int    u##K   = (UU);                                              \
    const int    row##K = ((u##K >> 3) << 1) + half;                         \
    const int    md##K  = u##K & 7;                                          \
    const float  bb##K  = s_beta[row##K][md##K];                             \
    const size_t a##K   = (size_t)row##K * 256 + md##K * 32 + l32;           \
    f32x4 v##K;                                                              \
    if (__all(bb##K == 0.0f)) { v##K = zero4; }                              \
    else { v##K = __builtin_nontemporal_load(&x4[a##K]); }

#define STOREU(K)                                                            \
    __builtin_nontemporal_store(v##K * bb##K, &o4[a##K]);

    // 32 units per wave; 4 groups of 8 in flight.
    #pragma unroll
    for (int g = 0; g < 4; ++g) {
        UNIT(0, wv + 32 * g +  0)
        UNIT(1, wv + 32 * g +  4)
        UNIT(2, wv + 32 * g +  8)
        UNIT(3, wv + 32 * g + 12)
        UNIT(4, wv + 32 * g + 16)
        UNIT(5, wv + 32 * g + 20)
        UNIT(6, wv + 32 * g + 24)
        UNIT(7, wv + 32 * g + 28)
        STOREU(0)
        STOREU(1)
        STOREU(2)
        STOREU(3)
        STOREU(4)
        STOREU(5)
        STOREU(6)
        STOREU(7)
    }

#undef UNIT
#undef STOREU
}

extern "C" void kernel_launch(void* const* d_in, const int* in_sizes, int n_in,
                              void* d_out, int out_size, void* d_ws, size_t ws_size,
                              hipStream_t stream) {
    const float* x      = (const float*)d_in[0];
    const float* q      = (const float*)d_in[1];
    const float* w      = (const float*)d_in[2];
    const float* b      = (const float*)d_in[3];
    const float* gammas = (const float*)d_in[4];
    const float* G      = (const float*)d_in[5];
    const float* bias   = (const float*)d_in[6];
    const float* qmin   = (const float*)d_in[7];
    float* out = (float*)d_out;

    emma_fused6<<<NROWS / RPB, 256, 0, stream>>>(
        x, q, w, b, gammas, G, bias, qmin, out);
}